// Round 11
// baseline (1332.367 us; speedup 1.0000x reference)
//
#include <hip/hip_runtime.h>
#include <cstddef>
#include <cstdint>

#define B_ 8192
#define S_ 14
#define K_ 512
#define D_ 256

// certification constant: |computed_score - true_score| <= CERT_C * |key_row|
// worst-case: split missing terms (km*mm + kl*m + k*ml) <= 1.15e-5, fp32
// accumulation <= 256*2^-24*|k||m| (Cauchy-Schwarz prefix bound) ~ 1.53e-5
// -> total ~ 2.7e-5.  CERT_C = 6e-5 keeps a 2.2x margin.
// Ambiguous rows (gap12 < 2eps) route:
//   I2 from a v1-slot AND V1-V3_ub > 2eps -> candidates provably {I1,I2}
//     (V3_ub = max of remaining 6 entries; includes every block's v2 which
//      bounds that block's unreported ks)        -> cheap fp64 pair-rescore
//   else (same-block top-2, or 3rd within window) -> full fp64 row rescore
#define CERT_C 6.0e-5f

typedef __attribute__((ext_vector_type(8))) short bfx8;
typedef __attribute__((ext_vector_type(4))) float fx4;

typedef __attribute__((address_space(3))) unsigned int       lds_u32;
typedef const __attribute__((address_space(1))) unsigned int glb_u32;

__device__ __forceinline__ void gload16(const void* g, void* l) {
    __builtin_amdgcn_global_load_lds((glb_u32*)g, (lds_u32*)l, 16, 0, 0);
}

// RNE float -> bf16 bits
__device__ __forceinline__ unsigned short f2bf(float x) {
    union { float f; unsigned int u; } v; v.f = x;
    unsigned int r = (v.u + 0x7FFFu + ((v.u >> 16) & 1u)) >> 16;
    return (unsigned short)r;
}
__device__ __forceinline__ float bf2f(unsigned short h) {
    union { unsigned int u; float f; } v; v.u = ((unsigned int)h) << 16;
    return v.f;
}

// top-2 insert (lattice order (value, -index)): (v,k) into (v1,i1)>=(v2,i2)
__device__ __forceinline__ void top2_ins(
    float v, int k, float& v1, int& i1, float& v2, int& i2)
{
    if (v > v1 || (v == v1 && k < i1)) {
        v2 = v1; i2 = i1; v1 = v; i1 = k;
    } else if (v > v2 || (v == v2 && k < i2)) {
        v2 = v; i2 = k;
    }
}

// ---------------------------------------------------------------------------
// per-row inverse L2 norm (fallback path helper)
// ---------------------------------------------------------------------------
__global__ __launch_bounds__(64) void rownorm_kernel(
    const float* __restrict__ rows, float* __restrict__ invn)
{
    const int row  = blockIdx.x;
    const int lane = threadIdx.x;
    const float4 v = *reinterpret_cast<const float4*>(rows + (size_t)row * D_ + lane * 4);
    float ss = v.x * v.x + v.y * v.y + v.z * v.z + v.w * v.w;
    #pragma unroll
    for (int m = 32; m >= 1; m >>= 1) ss += __shfl_xor(ss, m, 64);
    if (lane == 0) invn[row] = 1.0f / fmaxf(sqrtf(ss), 1e-12f);
}

// ---------------------------------------------------------------------------
// 2-plane bf16 split of key (B,S,D) fp32 -> (S,B,D) planes + |key_row|
// 256 thr = 4 waves, one row per wave
// ---------------------------------------------------------------------------
__global__ __launch_bounds__(256) void split_key2_kernel(
    const float* __restrict__ key,
    unsigned short* __restrict__ ph, unsigned short* __restrict__ pm,
    float* __restrict__ keynorm)
{
    const int w    = threadIdx.x >> 6;
    const int lane = threadIdx.x & 63;
    const int b    = blockIdx.x * 4 + w;
    const int s    = blockIdx.y;
    const float4 x = *reinterpret_cast<const float4*>(
        key + ((size_t)b * S_ + s) * D_ + lane * 4);
    const size_t o = ((size_t)s * B_ + b) * D_ + lane * 4;

    float xs[4] = { x.x, x.y, x.z, x.w };
    unsigned short hh[4], mm[4];
    #pragma unroll
    for (int i = 0; i < 4; ++i) {
        unsigned short a = f2bf(xs[i]);
        float r1 = xs[i] - bf2f(a);
        hh[i] = a; mm[i] = f2bf(r1);
    }
    *reinterpret_cast<ushort4*>(ph + o) = make_ushort4(hh[0], hh[1], hh[2], hh[3]);
    *reinterpret_cast<ushort4*>(pm + o) = make_ushort4(mm[0], mm[1], mm[2], mm[3]);

    float ss = x.x * x.x + x.y * x.y + x.z * x.z + x.w * x.w;
    #pragma unroll
    for (int m = 32; m >= 1; m >>= 1) ss += __shfl_xor(ss, m, 64);
    if (lane == 0) keynorm[(size_t)s * B_ + b] = sqrtf(ss);
}

// ---------------------------------------------------------------------------
// fused: 2-plane bf16 split of (S,K,D) rows + inverse L2 norm per row
// ---------------------------------------------------------------------------
__global__ __launch_bounds__(64) void splitnorm_mem2_kernel(
    const float* __restrict__ mem,
    unsigned short* __restrict__ ph, unsigned short* __restrict__ pm,
    float* __restrict__ invn)
{
    const int row  = blockIdx.x;          // s*K + k
    const int lane = threadIdx.x;
    const size_t e = (size_t)row * D_ + lane * 4;
    const float4 x = *reinterpret_cast<const float4*>(mem + e);

    float xs[4] = { x.x, x.y, x.z, x.w };
    unsigned short hh[4], mm[4];
    #pragma unroll
    for (int i = 0; i < 4; ++i) {
        unsigned short a = f2bf(xs[i]);
        float r1 = xs[i] - bf2f(a);
        hh[i] = a; mm[i] = f2bf(r1);
    }
    *reinterpret_cast<ushort4*>(ph + e) = make_ushort4(hh[0], hh[1], hh[2], hh[3]);
    *reinterpret_cast<ushort4*>(pm + e) = make_ushort4(mm[0], mm[1], mm[2], mm[3]);

    float ss = x.x * x.x + x.y * x.y + x.z * x.z + x.w * x.w;
    #pragma unroll
    for (int m = 32; m >= 1; m >>= 1) ss += __shfl_xor(ss, m, 64);
    if (lane == 0) invn[row] = 1.0f / fmaxf(sqrtf(ss), 1e-12f);
}

// ---------------------------------------------------------------------------
// 3-pair MFMA score GEMM + per-block TOP-2 (with both indices) partials.
// Main loop = round-8 verified (141.5us, absmax 0.0) -- UNCHANGED.
// Epilogue = round-8 shape (4 LDS arrays, conflict-free) + i2 tracking.
// ---------------------------------------------------------------------------
__global__ __launch_bounds__(256, 3) void gemm_argmax3_kernel(
    const unsigned short* __restrict__ kh, const unsigned short* __restrict__ km,
    const unsigned short* __restrict__ mh, const unsigned short* __restrict__ mm_,
    const float* __restrict__ invn,
    float* __restrict__ pV1, int* __restrict__ pI1,
    float* __restrict__ pV2, int* __restrict__ pI2)
{
    __shared__ short T[4][128 * 32];   // 0..1 = key h/m, 2..3 = mem h/m
    __shared__ float sInv[128];
    __shared__ float bV1[128][2];
    __shared__ int   bI1[128][2];
    __shared__ float bV2[128][2];
    __shared__ int   bI2[128][2];

    // bijective XCD swizzle (nwg = 3584 = 8*448)
    const int orig = blockIdx.x;
    const int wg   = (orig & 7) * 448 + (orig >> 3);
    const int by   = wg & 3;          // k-block (fastest: key-tile sharers adjacent)
    const int bx   = (wg >> 2) & 63;  // b-block
    const int s    = wg >> 8;

    const int t    = threadIdx.x;
    const int b0   = bx * 128;
    const int n0   = by * 128;
    const int w    = t >> 6;
    const int lane = t & 63;
    const int wm   = w >> 1, wn = w & 1;
    const int lr   = lane & 15, lg = lane >> 4;

    const size_t sB = (size_t)s * B_;
    const size_t sK = (size_t)s * K_;

    const unsigned short* __restrict__ APl[2] = { kh, km };
    const unsigned short* __restrict__ BPl[2] = { mh, mm_ };

    fx4 acc[4][4];
    #pragma unroll
    for (int i = 0; i < 4; ++i)
        #pragma unroll
        for (int j = 0; j < 4; ++j) acc[i][j] = (fx4)0.0f;

    // staging: lane covers (row = l>>2, phys chunk = l&3);
    // pre-swizzled source chunk = (l&3) ^ ((l>>3)&3)
    const int rsub = lane >> 2;
    const int csw  = (((lane & 3) ^ ((lane >> 3) & 3)) * 8);
    // read-side: phys chunk = lg ^ ((row>>1)&3)
    const int rdof = ((lg ^ ((lr >> 1) & 3)) * 8);

    for (int dc = 0; dc < 8; ++dc) {
        // ---- stage 4 tiles (8 gload16/thread) ----
        const int dco = dc * 32 + csw;
        #pragma unroll
        for (int p = 0; p < 2; ++p) {
            #pragma unroll
            for (int u = 0; u < 2; ++u) {
                const int R0 = w * 32 + u * 16;
                gload16(APl[p] + (sB + b0 + R0 + rsub) * D_ + dco, &T[p][R0 * 32]);
                gload16(BPl[p] + (sK + n0 + R0 + rsub) * D_ + dco, &T[2 + p][R0 * 32]);
            }
        }
        __syncthreads();   // vmcnt(0) drain: all 4 tiles resident

        // ---- hoist B fragments once (8 ds_read_b128) ----
        bfx8 bf[2][4];
        #pragma unroll
        for (int bp = 0; bp < 2; ++bp)
            #pragma unroll
            for (int j = 0; j < 4; ++j)
                bf[bp][j] = *reinterpret_cast<const bfx8*>(
                    &T[2 + bp][(wn * 64 + j * 16 + lr) * 32 + rdof]);

        // ---- 3 term-pairs: (0,0)(0,1)(1,0) ----
        #pragma unroll
        for (int ap = 0; ap < 2; ++ap) {
            bfx8 af[4];
            #pragma unroll
            for (int i = 0; i < 4; ++i)
                af[i] = *reinterpret_cast<const bfx8*>(
                    &T[ap][(wm * 64 + i * 16 + lr) * 32 + rdof]);
            #pragma unroll
            for (int bp = 0; bp < 2 - ap; ++bp) {
                __builtin_amdgcn_s_setprio(1);
                #pragma unroll
                for (int i = 0; i < 4; ++i)
                    #pragma unroll
                    for (int j = 0; j < 4; ++j)
                        acc[i][j] = __builtin_amdgcn_mfma_f32_16x16x32_bf16(
                            af[i], bf[bp][j], acc[i][j], 0, 0, 0);
                __builtin_amdgcn_s_setprio(0);
            }
        }
        __syncthreads();   // everyone done reading before next stage overwrites
    }

    if (t < 128) sInv[t] = invn[sK + n0 + t];
    __syncthreads();

    #pragma unroll
    for (int i = 0; i < 4; ++i) {
        #pragma unroll
        for (int r = 0; r < 4; ++r) {
            float v1 = -3.4e38f, v2 = -3.4e38f;
            int i1 = 0x7fffffff, i2 = 0x7fffffff;
            #pragma unroll
            for (int j = 0; j < 4; ++j) {
                const int kloc = wn * 64 + j * 16 + lr;
                top2_ins(acc[i][j][r] * sInv[kloc], n0 + kloc, v1, i1, v2, i2);
            }
            #pragma unroll
            for (int msk = 1; msk < 16; msk <<= 1) {
                const float ov1 = __shfl_xor(v1, msk, 64);
                const int   oi1 = __shfl_xor(i1, msk, 64);
                const float ov2 = __shfl_xor(v2, msk, 64);
                const int   oi2 = __shfl_xor(i2, msk, 64);
                top2_ins(ov1, oi1, v1, i1, v2, i2);
                top2_ins(ov2, oi2, v1, i1, v2, i2);
            }
            if (lr == 0) {
                const int mrow = wm * 64 + i * 16 + lg * 4 + r;
                bV1[mrow][wn] = v1; bI1[mrow][wn] = i1;
                bV2[mrow][wn] = v2; bI2[mrow][wn] = i2;
            }
        }
    }
    __syncthreads();

    if (t < 128) {
        float v1 = bV1[t][0], v2 = bV2[t][0];
        int   i1 = bI1[t][0], i2 = bI2[t][0];
        top2_ins(bV1[t][1], bI1[t][1], v1, i1, v2, i2);
        top2_ins(bV2[t][1], bI2[t][1], v1, i1, v2, i2);
        const size_t o = ((size_t)s * 4 + by) * B_ + b0 + t;
        pV1[o] = v1; pI1[o] = i1; pV2[o] = v2; pI2[o] = i2;
    }
}

// ---------------------------------------------------------------------------
// merge 4 n-block top-2 partials positionally -> ind; route ambiguous rows.
// Entries: pos 2*nb = (v1,i1) of block nb, pos 2*nb+1 = (v2,i2).
// pass1 -> (V1,pos1); pass2 (excl pos1) -> (V2,I2,pos2); pass3 -> V3_ub.
// pos2 odd  => I1,I2 same block => that block's unreported unbounded -> full.
// pos2 even => V3_ub covers all other reported + every block's unreported.
// ---------------------------------------------------------------------------
__global__ __launch_bounds__(256) void combine_cert2_kernel(
    const float* __restrict__ pV1, const int* __restrict__ pI1,
    const float* __restrict__ pV2, const int* __restrict__ pI2,
    const float* __restrict__ keynorm,
    int* __restrict__ ind, int* __restrict__ cand2,
    int* __restrict__ pairCnt, int* __restrict__ pairList,
    int* __restrict__ fullCnt, int* __restrict__ fullList)
{
    const int idx = blockIdx.x * 256 + threadIdx.x;   // s*B + b
    const int s   = idx >> 13;                        // B_=8192
    const int b   = idx & 8191;

    float ev[8]; int ei[8];
    #pragma unroll
    for (int nb = 0; nb < 4; ++nb) {
        const size_t o = ((size_t)s * 4 + nb) * B_ + b;
        ev[2 * nb]     = pV1[o]; ei[2 * nb]     = pI1[o];
        ev[2 * nb + 1] = pV2[o]; ei[2 * nb + 1] = pI2[o];
    }

    // pass 1: global top-1
    float V1 = -3.4e38f; int I1 = 0x7fffffff, pos1 = -1;
    #pragma unroll
    for (int p = 0; p < 8; ++p)
        if (ev[p] > V1 || (ev[p] == V1 && ei[p] < I1)) { V1 = ev[p]; I1 = ei[p]; pos1 = p; }
    // pass 2: top-2 (exclude pos1)
    float V2 = -3.4e38f; int I2 = 0x7fffffff, pos2 = -1;
    #pragma unroll
    for (int p = 0; p < 8; ++p)
        if (p != pos1 && (ev[p] > V2 || (ev[p] == V2 && ei[p] < I2))) { V2 = ev[p]; I2 = ei[p]; pos2 = p; }
    // pass 3: value bound on 3rd place (exclude pos1, pos2)
    float V3 = -3.4e38f;
    #pragma unroll
    for (int p = 0; p < 8; ++p)
        if (p != pos1 && p != pos2) V3 = fmaxf(V3, ev[p]);

    ind[idx] = I1;
    const float eps2 = 2.0f * CERT_C * keynorm[idx];
    if (V1 - V2 < eps2) {
        if (((pos2 & 1) == 0) && (V1 - V3 > eps2)) {
            cand2[idx] = I2;
            const int p = atomicAdd(pairCnt, 1);
            pairList[p] = idx;
        } else {
            const int p = atomicAdd(fullCnt, 1);
            fullList[p] = idx;
        }
    }
}

__global__ __launch_bounds__(64) void zero4_kernel(
    int* __restrict__ c1, int* __restrict__ c2,
    int* __restrict__ c3, int* __restrict__ c4)
{
    if (threadIdx.x == 0) { *c1 = 0; *c2 = 0; *c3 = 0; *c4 = 0; }
}

// ---------------------------------------------------------------------------
// cheap fp64 pair-rescore: candidates {ind[row], cand2[row]} only.
// One wave per list entry (4 waves/block, grid-stride).  ~3KB reads/row.
// ---------------------------------------------------------------------------
__global__ __launch_bounds__(256) void rescore_pair_kernel(
    const int* __restrict__ pairCnt, const int* __restrict__ pairList,
    const float* __restrict__ key, const float* __restrict__ mem,
    const float* __restrict__ invn, const int* __restrict__ cand2,
    int* __restrict__ ind)
{
    const int n    = *pairCnt;
    const int w    = threadIdx.x >> 6;
    const int lane = threadIdx.x & 63;
    for (int li = blockIdx.x * 4 + w; li < n; li += gridDim.x * 4) {
        const int row = pairList[li];
        const int s = row >> 13, b = row & 8191;
        const int i1 = ind[row], i2 = cand2[row];
        const float4 kv = *reinterpret_cast<const float4*>(
            key + ((size_t)b * S_ + s) * D_ + lane * 4);
        const float4 m1 = *reinterpret_cast<const float4*>(
            mem + ((size_t)s * K_ + i1) * D_ + lane * 4);
        const float4 m2 = *reinterpret_cast<const float4*>(
            mem + ((size_t)s * K_ + i2) * D_ + lane * 4);
        double d1 = (double)kv.x * m1.x + (double)kv.y * m1.y
                  + (double)kv.z * m1.z + (double)kv.w * m1.w;
        double d2 = (double)kv.x * m2.x + (double)kv.y * m2.y
                  + (double)kv.z * m2.z + (double)kv.w * m2.w;
        #pragma unroll
        for (int m = 32; m >= 1; m >>= 1) {
            d1 += __shfl_xor(d1, m, 64);
            d2 += __shfl_xor(d2, m, 64);
        }
        if (lane == 0) {
            const double sc1 = d1 * (double)invn[(size_t)s * K_ + i1];
            const double sc2 = d2 * (double)invn[(size_t)s * K_ + i2];
            const bool take2 = (sc2 > sc1) || (sc2 == sc1 && i2 < i1);
            if (take2) ind[row] = i2;
        }
    }
}

// ---------------------------------------------------------------------------
// full fp64 rescore (round-9 verified coalesced version).
// One row per block; 4 waves x 128 k.
// ---------------------------------------------------------------------------
__global__ __launch_bounds__(256) void rescore_full_kernel(
    const int* __restrict__ fullCnt, const int* __restrict__ fullList,
    const float* __restrict__ key, const float* __restrict__ mem,
    const float* __restrict__ invn, int* __restrict__ ind)
{
    __shared__ double sV[4];
    __shared__ int    sI[4];
    const int n    = *fullCnt;
    const int t    = threadIdx.x;
    const int w    = t >> 6;
    const int lane = t & 63;
    for (int li = blockIdx.x; li < n; li += gridDim.x) {
        const int row = fullList[li];
        const int s = row >> 13, b = row & 8191;
        const float4 kv = *reinterpret_cast<const float4*>(
            key + ((size_t)b * S_ + s) * D_ + lane * 4);
        const double k0 = kv.x, k1 = kv.y, k2 = kv.z, k3 = kv.w;
        const float* __restrict__ mbase = mem + (size_t)s * K_ * D_;
        const float* __restrict__ ibase = invn + (size_t)s * K_;

        double bv = -1.0e300; int bk = 0x7fffffff;
        for (int kq = 0; kq < 128; kq += 4) {
            double d[4];
            #pragma unroll
            for (int u = 0; u < 4; ++u) {
                const int k = w * 128 + kq + u;
                const float4 mv = *reinterpret_cast<const float4*>(
                    mbase + (size_t)k * D_ + lane * 4);
                d[u] = k0 * mv.x + k1 * mv.y + k2 * mv.z + k3 * mv.w;
            }
            #pragma unroll
            for (int m = 32; m >= 1; m >>= 1)
                #pragma unroll
                for (int u = 0; u < 4; ++u) d[u] += __shfl_xor(d[u], m, 64);
            #pragma unroll
            for (int u = 0; u < 4; ++u) {
                const int k = w * 128 + kq + u;
                const double sc = d[u] * (double)ibase[k];
                if (sc > bv || (sc == bv && k < bk)) { bv = sc; bk = k; }
            }
        }
        if (lane == 0) { sV[w] = bv; sI[w] = bk; }
        __syncthreads();
        if (t == 0) {
            double v = sV[0]; int bi = sI[0];
            #pragma unroll
            for (int g = 1; g < 4; ++g)
                if (sV[g] > v || (sV[g] == v && sI[g] < bi)) { v = sV[g]; bi = sI[g]; }
            ind[row] = bi;
        }
        __syncthreads();
    }
}

// ---------------------------------------------------------------------------
// out[b][s][:] = value[b][0][:] + newmem[s][ind2[s*B+b]][:]
// ---------------------------------------------------------------------------
__global__ __launch_bounds__(256) void gather_out_kernel(
    const int* __restrict__ ind2, const float* __restrict__ value,
    const float* __restrict__ newmem, float* __restrict__ out)
{
    const int row  = blockIdx.x * 4 + (threadIdx.x >> 6);  // s*B + b
    const int lane = threadIdx.x & 63;
    const int s    = row >> 13;
    const int b    = row & 8191;
    const int bi   = ind2[row];
    const float4 vv = *reinterpret_cast<const float4*>(
        value + (size_t)b * (S_ * D_) + lane * 4);          // value[b][0][:]
    const float4 mmv = *reinterpret_cast<const float4*>(
        newmem + ((size_t)s * K_ + bi) * D_ + lane * 4);
    float4 o4;
    o4.x = vv.x + mmv.x; o4.y = vv.y + mmv.y;
    o4.z = vv.z + mmv.z; o4.w = vv.w + mmv.w;
    *reinterpret_cast<float4*>(out + ((size_t)b * S_ + s) * D_ + lane * 4) = o4;
}

// ---------------------------------------------------------------------------
// update chain: deterministic chunked counting sort + gather-EMA (unchanged)
// ---------------------------------------------------------------------------
__global__ __launch_bounds__(256) void u1_hist_kernel(
    const int* __restrict__ ind1, int* __restrict__ hist)
{
    __shared__ int h[K_];
    const int t = threadIdx.x, c = blockIdx.x, s = blockIdx.y;
    h[t] = 0; h[t + 256] = 0;
    __syncthreads();
    const int k = ind1[(size_t)s * B_ + c * 256 + t];
    atomicAdd(&h[k], 1);
    __syncthreads();
    hist[((size_t)s * 32 + c) * K_ + t]       = h[t];
    hist[((size_t)s * 32 + c) * K_ + t + 256] = h[t + 256];
}

__global__ __launch_bounds__(512) void u2_scan_kernel(
    int* __restrict__ hist, int* __restrict__ cnt, int* __restrict__ offs)
{
    __shared__ int sc[K_];
    const int k = threadIdx.x, s = blockIdx.x;
    int run = 0;
    for (int c = 0; c < 32; ++c) {
        const size_t o = ((size_t)s * 32 + c) * K_ + k;
        const int x = hist[o];
        hist[o] = run;           // exclusive per-chunk base within slot
        run += x;
    }
    cnt[s * K_ + k] = run;
    sc[k] = run;
    __syncthreads();
    for (int off = 1; off < K_; off <<= 1) {
        int v = (k >= off) ? sc[k - off] : 0;
        __syncthreads();
        sc[k] += v;
        __syncthreads();
    }
    offs[s * K_ + k] = sc[k] - run;   // exclusive slot base
}

__global__ __launch_bounds__(256) void u3_scatter_kernel(
    const int* __restrict__ ind1, const int* __restrict__ hist,
    const int* __restrict__ offs, int* __restrict__ csr)
{
    __shared__ int sk[256];
    const int t = threadIdx.x, c = blockIdx.x, s = blockIdx.y;
    const int b = c * 256 + t;
    const int k = ind1[(size_t)s * B_ + b];
    sk[t] = k;
    __syncthreads();
    int rank = 0;
    for (int j = 0; j < t; ++j) rank += (sk[j] == k);
    const int pos = offs[s * K_ + k] + hist[((size_t)s * 32 + c) * K_ + k] + rank;
    csr[(size_t)s * B_ + pos] = b;
}

__global__ __launch_bounds__(64) void u4_gather_kernel(
    const int* __restrict__ csr, const int* __restrict__ cnt,
    const int* __restrict__ offs, const float* __restrict__ value,
    const float* __restrict__ memory, float* __restrict__ newmem)
{
    const int k = blockIdx.x, s = blockIdx.y, lane = threadIdx.x;
    const int n = cnt[s * K_ + k];
    const int base = offs[s * K_ + k];
    float4 a; a.x = a.y = a.z = a.w = 0.0f;
    for (int i = 0; i < n; ++i) {
        const int b = csr[(size_t)s * B_ + base + i];
        const float4 v = *reinterpret_cast<const float4*>(
            value + ((size_t)b * S_ + s) * D_ + lane * 4);
        a.x += v.x; a.y += v.y; a.z += v.z; a.w += v.w;
    }
    const float inv = 1.0f / ((float)n + 1e-6f);
    const size_t o = ((size_t)s * K_ + k) * D_ + lane * 4;
    const float4 mo = *reinterpret_cast<const float4*>(memory + o);
    float4 r;
    r.x = mo.x * 0.999f + a.x * inv * 0.001f;
    r.y = mo.y * 0.999f + a.y * inv * 0.001f;
    r.z = mo.z * 0.999f + a.z * inv * 0.001f;
    r.w = mo.w * 0.999f + a.w * inv * 0.001f;
    *reinterpret_cast<float4*>(newmem + o) = r;
}

// ===========================================================================
// FALLBACK (round-1 verified fp32 path; used if ws too small)
// ===========================================================================
template <int MODE>
__global__ __launch_bounds__(256) void score_argmax_kernel(
    const float* __restrict__ key, const float* __restrict__ mem,
    const float* __restrict__ invn, const float* __restrict__ value,
    float* __restrict__ out, int* __restrict__ ind_out)
{
    __shared__ __align__(16) float kt[64][36];
    __shared__ __align__(16) float mt[64][36];
    __shared__ float redV[64][16];
    __shared__ int   redI[64][16];

    const int t  = threadIdx.x;
    const int s  = blockIdx.y;
    const int b0 = blockIdx.x * 64;
    const int tb = t & 15;
    const int tk = t >> 4;

    float best[4]; int bidx[4];
    #pragma unroll
    for (int i = 0; i < 4; ++i) { best[i] = -3.4e38f; bidx[i] = 0; }

    for (int kc = 0; kc < 8; ++kc) {
        float acc[4][4];
        #pragma unroll
        for (int i = 0; i < 4; ++i)
            #pragma unroll
            for (int j = 0; j < 4; ++j) acc[i][j] = 0.0f;

        for (int dc = 0; dc < 8; ++dc) {
            #pragma unroll
            for (int u = 0; u < 2; ++u) {
                const int f = t + u * 256;
                const int row = f >> 3;
                const int c4 = f & 7;
                *reinterpret_cast<float4*>(&kt[row][c4 * 4]) =
                    *reinterpret_cast<const float4*>(
                        key + (((size_t)(b0 + row)) * S_ + s) * D_ + dc * 32 + c4 * 4);
                *reinterpret_cast<float4*>(&mt[row][c4 * 4]) =
                    *reinterpret_cast<const float4*>(
                        mem + (((size_t)s * K_) + kc * 64 + row) * D_ + dc * 32 + c4 * 4);
            }
            __syncthreads();
            #pragma unroll
            for (int d4 = 0; d4 < 8; ++d4) {
                float4 a[4], b[4];
                #pragma unroll
                for (int i = 0; i < 4; ++i)
                    a[i] = *reinterpret_cast<const float4*>(&kt[tb + i * 16][d4 * 4]);
                #pragma unroll
                for (int j = 0; j < 4; ++j)
                    b[j] = *reinterpret_cast<const float4*>(&mt[tk + j * 16][d4 * 4]);
                #pragma unroll
                for (int i = 0; i < 4; ++i)
                    #pragma unroll
                    for (int j = 0; j < 4; ++j)
                        acc[i][j] += a[i].x * b[j].x + a[i].y * b[j].y +
                                     a[i].z * b[j].z + a[i].w * b[j].w;
            }
            __syncthreads();
        }
        #pragma unroll
        for (int j = 0; j < 4; ++j) {
            const int kabs = kc * 64 + tk + j * 16;
            const float inv = invn[s * K_ + kabs];
            #pragma unroll
            for (int i = 0; i < 4; ++i) {
                const float v = acc[i][j] * inv;
                if (v > best[i] || (v == best[i] && kabs < bidx[i])) {
                    best[i] = v; bidx[i] = kabs;
                }
            }
        }
    }
    #pragma unroll
    for (int i = 0; i < 4; ++i) {
        redV[tb + i * 16][tk] = best[i];
        redI[tb + i * 16][tk] = bidx[i];
    }
    __syncthreads();
    if (t < 64) {
        float bv = redV[t][0]; int bi = redI[t][0];
        #pragma unroll
        for (int g = 1; g < 16; ++g) {
            const float v = redV[t][g]; const int ix = redI[t][g];
            if (v > bv || (v == bv && ix < bi)) { bv = v; bi = ix; }
        }
        if (MODE == 0) ind_out[(size_t)s * B_ + b0 + t] = bi;
        else           redI[t][0] = bi;
    }
    if (MODE == 1) {
        __syncthreads();
        const int w = t >> 6, lane = t & 63;
        for (int r = w; r < 64; r += 4) {
            const int bg = b0 + r;
            const int kk = redI[r][0];
            const float4 vv = *reinterpret_cast<const float4*>(
                value + (size_t)bg * (S_ * D_) + lane * 4);
            const float4 mmv = *reinterpret_cast<const float4*>(
                mem + ((size_t)s * K_ + kk) * D_ + lane * 4);
            float4 o;
            o.x = vv.x + mmv.x; o.y = vv.y + mmv.y;
            o.z = vv.z + mmv.z; o.w = vv.w + mmv.w;
            *reinterpret_cast<float4*>(
                out + (((size_t)bg) * S_ + s) * D_ + lane * 4) = o;
        }
    }
}

__global__ __launch_bounds__(256) void update_kernel(
    const int* __restrict__ ind1, const float* __restrict__ value,
    const float* __restrict__ memory, float* __restrict__ newmem)
{
    const int k0 = blockIdx.x * 4, s = blockIdx.y, t = threadIdx.x;
    __shared__ int sIdx[256];
    float a0 = 0.f, a1 = 0.f, a2 = 0.f, a3 = 0.f;
    int c0 = 0, c1 = 0, c2 = 0, c3 = 0;
    for (int b0 = 0; b0 < B_; b0 += 256) {
        sIdx[t] = ind1[(size_t)s * B_ + b0 + t];
        __syncthreads();
        for (int bb = 0; bb < 256; ++bb) {
            const int ix = sIdx[bb];
            const unsigned r = (unsigned)(ix - k0);
            if (r < 4u) {
                const float v = value[(((size_t)(b0 + bb)) * S_ + s) * D_ + t];
                if      (r == 0u) { a0 += v; ++c0; }
                else if (r == 1u) { a1 += v; ++c1; }
                else if (r == 2u) { a2 += v; ++c2; }
                else              { a3 += v; ++c3; }
            }
        }
        __syncthreads();
    }
    const float accs[4] = { a0, a1, a2, a3 };
    const int   cns [4] = { c0, c1, c2, c3 };
    #pragma unroll
    for (int kk = 0; kk < 4; ++kk) {
        const size_t off = ((size_t)s * K_ + k0 + kk) * D_ + t;
        const float mean = accs[kk] / ((float)cns[kk] + 1e-6f);
        newmem[off] = memory[off] * 0.999f + mean * 0.001f;
    }
}

// ---------------------------------------------------------------------------
extern "C" void kernel_launch(void* const* d_in, const int* in_sizes, int n_in,
                              void* d_out, int out_size, void* d_ws, size_t ws_size,
                              hipStream_t stream)
{
    const float* key    = (const float*)d_in[0];
    const float* value  = (const float*)d_in[1];
    const float* memory = (const float*)d_in[2];

    float* out    = (float*)d_out;                       // (B,S,D)
    float* newmem = out + (size_t)B_ * S_ * D_;          // (S,K,D)

    // ---- workspace layout for the MFMA path ----
    const size_t keyPlane = (size_t)S_ * B_ * D_;        // elems (bf16)
    const size_t memPlane = (size_t)S_ * K_ * D_;
    char* p = (char*)d_ws;
    size_t need = 0;
    auto alloc = [&](size_t bytes) -> char* {
        char* r = p + need;
        need += (bytes + 255) & ~(size_t)255;
        return r;
    };
    unsigned short* kh   = (unsigned short*)alloc(keyPlane * 2);
    unsigned short* km   = (unsigned short*)alloc(keyPlane * 2);
    unsigned short* mh   = (unsigned short*)alloc(memPlane * 2);
    unsigned short* mm   = (unsigned short*)alloc(memPlane * 2);
    float* invn    = (float*)alloc((size_t)S_ * K_ * 4);
    float* keynorm = (float*)alloc((size_t)S_ * B_ * 4);
    float* pV1     = (float*)alloc((size_t)S_ * 4 * B_ * 4);
    int*   pI1     = (int*)  alloc((size_t)S_ * 4 * B_ * 4);
    float* pV2     = (float*)alloc((size_t)S_ * 4 * B_ * 4);
    int*   pI2     = (int*)  alloc((size_t)S_ * 4 * B_ * 4);
    int*   ind1    = (int*)  alloc((size_t)S_ * B_ * 4);
    int*   ind2    = (int*)  alloc((size_t)S_ * B_ * 4);
    int*   cand2   = (int*)  alloc((size_t)S_ * B_ * 4);
    int*   pr1Cnt  = (int*)  alloc(256);
    int*   fu1Cnt  = (int*)  alloc(256);
    int*   pr2Cnt  = (int*)  alloc(256);
    int*   fu2Cnt  = (int*)  alloc(256);
    int*   pr1Lst  = (int*)  alloc((size_t)S_ * B_ * 4);
    int*   fu1Lst  = (int*)  alloc((size_t)S_ * B_ * 4);
    int*   pr2Lst  = (int*)  alloc((size_t)S_ * B_ * 4);
    int*   fu2Lst  = (int*)  alloc((size_t)S_ * B_ * 4);
    int*   hist    = (int*)  alloc((size_t)S_ * 32 * K_ * 4);
    int*   cnt     = (int*)  alloc((size_t)S_ * K_ * 4);
    int*   offs    = (int*)  alloc((size_t)S_ * K_ * 4);
    int*   csr     = (int*)  alloc((size_t)S_ * B_ * 4);

    if (ws_size >= need) {
        // ================= fast MFMA path =================
        split_key2_kernel<<<dim3(B_ / 4, S_), 256, 0, stream>>>(key, kh, km, keynorm);
        splitnorm_mem2_kernel<<<dim3(S_ * K_), 64, 0, stream>>>(memory, mh, mm, invn);
        zero4_kernel<<<dim3(1), 64, 0, stream>>>(pr1Cnt, fu1Cnt, pr2Cnt, fu2Cnt);

        gemm_argmax3_kernel<<<dim3(3584), 256, 0, stream>>>(
            kh, km, mh, mm, invn, pV1, pI1, pV2, pI2);
        combine_cert2_kernel<<<dim3((S_ * B_) / 256), 256, 0, stream>>>(
            pV1, pI1, pV2, pI2, keynorm, ind1, cand2,
            pr1Cnt, pr1Lst, fu1Cnt, fu1Lst);
        rescore_pair_kernel<<<dim3(1024), 256, 0, stream>>>(
            pr1Cnt, pr1Lst, key, memory, invn, cand2, ind1);
        rescore_full_kernel<<<dim3(512), 256, 0, stream>>>(
            fu1Cnt, fu1Lst, key, memory, invn, ind1);

        u1_hist_kernel<<<dim3(32, S_), 256, 0, stream>>>(ind1, hist);
        u2_scan_kernel<<<dim3(S_), 512, 0, stream>>>(hist, cnt, offs);
        u3_scatter_kernel<<<dim3(32, S_), 256, 0, stream>>>(ind1, hist, offs, csr);
        u4_gather_kernel<<<dim3(K_, S_), 64, 0, stream>>>(csr, cnt, offs, value, memory, newmem);

        splitnorm_mem2_kernel<<<dim3(S_ * K_), 64, 0, stream>>>(newmem, mh, mm, invn);

        gemm_argmax3_kernel<<<dim3(3584), 256, 0, stream>>>(
            kh, km, mh, mm, invn, pV1, pI1, pV2, pI2);
        combine_cert2_kernel<<<dim3((S_ * B_) / 256), 256, 0, stream>>>(
            pV1, pI1, pV2, pI2, keynorm, ind2, cand2,
            pr2Cnt, pr2Lst, fu2Cnt, fu2Lst);
        rescore_pair_kernel<<<dim3(1024), 256, 0, stream>>>(
            pr2Cnt, pr2Lst, key, newmem, invn, cand2, ind2);
        rescore_full_kernel<<<dim3(512), 256, 0, stream>>>(
            fu2Cnt, fu2Lst, key, newmem, invn, ind2);

        gather_out_kernel<<<dim3((S_ * B_) / 4), 256, 0, stream>>>(
            ind2, value, newmem, out);
    } else {
        // ================= fallback fp32 path (round-1, verified) =================
        float* invn1 = (float*)d_ws;
        float* invn2 = invn1 + S_ * K_;
        int*   find1 = (int*)(invn2 + S_ * K_);

        rownorm_kernel<<<dim3(S_ * K_), 64, 0, stream>>>(memory, invn1);
        score_argmax_kernel<0><<<dim3(B_ / 64, S_), 256, 0, stream>>>(
            key, memory, invn1, nullptr, nullptr, find1);
        update_kernel<<<dim3(K_ / 4, S_), 256, 0, stream>>>(find1, value, memory, newmem);
        rownorm_kernel<<<dim3(S_ * K_), 64, 0, stream>>>(newmem, invn2);
        score_argmax_kernel<1><<<dim3(B_ / 64, S_), 256, 0, stream>>>(
            key, newmem, invn2, value, out, nullptr);
    }
}

// Round 12
// 484.169 us; speedup vs baseline: 2.7519x; 2.7519x over previous
//
#include <hip/hip_runtime.h>
#include <cstddef>
#include <cstdint>

#define B_ 8192
#define S_ 14
#define K_ 512
#define D_ 256

// certification constant: |computed_score - true_score| <= CERT_C * |key_row|
// worst-case: split missing terms (km*mm + kl*m + k*ml) <= 1.15e-5, fp32
// accumulation <= 256*2^-24*|k||m| (Cauchy-Schwarz prefix bound) ~ 1.53e-5
// -> total ~ 2.7e-5.  CERT_C = 6e-5 keeps a 2.2x margin.  Rows with
// top2-gap < 2*eps are exactly rescored in fp64 (validated absmax 0.0 in
// rounds 8-11).  Rescore skips blocks whose top-1 < V1-2eps: every k there
// has true_k <= v1_blk + eps < V1 - eps <= true_I1 (strict) -- provably
// not the argmax, nor tied with it.
#define CERT_C 6.0e-5f

typedef __attribute__((ext_vector_type(8))) short bfx8;
typedef __attribute__((ext_vector_type(4))) float fx4;

typedef __attribute__((address_space(3))) unsigned int       lds_u32;
typedef const __attribute__((address_space(1))) unsigned int glb_u32;

__device__ __forceinline__ void gload16(const void* g, void* l) {
    __builtin_amdgcn_global_load_lds((glb_u32*)g, (lds_u32*)l, 16, 0, 0);
}

// RNE float -> bf16 bits
__device__ __forceinline__ unsigned short f2bf(float x) {
    union { float f; unsigned int u; } v; v.f = x;
    unsigned int r = (v.u + 0x7FFFu + ((v.u >> 16) & 1u)) >> 16;
    return (unsigned short)r;
}
__device__ __forceinline__ float bf2f(unsigned short h) {
    union { unsigned int u; float f; } v; v.u = ((unsigned int)h) << 16;
    return v.f;
}

// ---------------------------------------------------------------------------
// per-row inverse L2 norm (fallback path helper)
// ---------------------------------------------------------------------------
__global__ __launch_bounds__(64) void rownorm_kernel(
    const float* __restrict__ rows, float* __restrict__ invn)
{
    const int row  = blockIdx.x;
    const int lane = threadIdx.x;
    const float4 v = *reinterpret_cast<const float4*>(rows + (size_t)row * D_ + lane * 4);
    float ss = v.x * v.x + v.y * v.y + v.z * v.z + v.w * v.w;
    #pragma unroll
    for (int m = 32; m >= 1; m >>= 1) ss += __shfl_xor(ss, m, 64);
    if (lane == 0) invn[row] = 1.0f / fmaxf(sqrtf(ss), 1e-12f);
}

// ---------------------------------------------------------------------------
// 2-plane bf16 split of key (B,S,D) fp32 -> (S,B,D) planes + |key_row|
// 256 thr = 4 waves, one row per wave
// ---------------------------------------------------------------------------
__global__ __launch_bounds__(256) void split_key2_kernel(
    const float* __restrict__ key,
    unsigned short* __restrict__ ph, unsigned short* __restrict__ pm,
    float* __restrict__ keynorm)
{
    const int w    = threadIdx.x >> 6;
    const int lane = threadIdx.x & 63;
    const int b    = blockIdx.x * 4 + w;
    const int s    = blockIdx.y;
    const float4 x = *reinterpret_cast<const float4*>(
        key + ((size_t)b * S_ + s) * D_ + lane * 4);
    const size_t o = ((size_t)s * B_ + b) * D_ + lane * 4;

    float xs[4] = { x.x, x.y, x.z, x.w };
    unsigned short hh[4], mm[4];
    #pragma unroll
    for (int i = 0; i < 4; ++i) {
        unsigned short a = f2bf(xs[i]);
        float r1 = xs[i] - bf2f(a);
        hh[i] = a; mm[i] = f2bf(r1);
    }
    *reinterpret_cast<ushort4*>(ph + o) = make_ushort4(hh[0], hh[1], hh[2], hh[3]);
    *reinterpret_cast<ushort4*>(pm + o) = make_ushort4(mm[0], mm[1], mm[2], mm[3]);

    float ss = x.x * x.x + x.y * x.y + x.z * x.z + x.w * x.w;
    #pragma unroll
    for (int m = 32; m >= 1; m >>= 1) ss += __shfl_xor(ss, m, 64);
    if (lane == 0) keynorm[(size_t)s * B_ + b] = sqrtf(ss);
}

// ---------------------------------------------------------------------------
// fused: 2-plane bf16 split of (S,K,D) rows + inverse L2 norm per row
// ---------------------------------------------------------------------------
__global__ __launch_bounds__(64) void splitnorm_mem2_kernel(
    const float* __restrict__ mem,
    unsigned short* __restrict__ ph, unsigned short* __restrict__ pm,
    float* __restrict__ invn)
{
    const int row  = blockIdx.x;          // s*K + k
    const int lane = threadIdx.x;
    const size_t e = (size_t)row * D_ + lane * 4;
    const float4 x = *reinterpret_cast<const float4*>(mem + e);

    float xs[4] = { x.x, x.y, x.z, x.w };
    unsigned short hh[4], mm[4];
    #pragma unroll
    for (int i = 0; i < 4; ++i) {
        unsigned short a = f2bf(xs[i]);
        float r1 = xs[i] - bf2f(a);
        hh[i] = a; mm[i] = f2bf(r1);
    }
    *reinterpret_cast<ushort4*>(ph + e) = make_ushort4(hh[0], hh[1], hh[2], hh[3]);
    *reinterpret_cast<ushort4*>(pm + e) = make_ushort4(mm[0], mm[1], mm[2], mm[3]);

    float ss = x.x * x.x + x.y * x.y + x.z * x.z + x.w * x.w;
    #pragma unroll
    for (int m = 32; m >= 1; m >>= 1) ss += __shfl_xor(ss, m, 64);
    if (lane == 0) invn[row] = 1.0f / fmaxf(sqrtf(ss), 1e-12f);
}

// ---------------------------------------------------------------------------
// 3-pair MFMA score GEMM + per-block TOP-2 argmax partials.
// [round-8/9 verified at 141.3-141.5us, absmax 0.0 -- VERBATIM, UNCHANGED]
// ---------------------------------------------------------------------------
__global__ __launch_bounds__(256, 3) void gemm_argmax3_kernel(
    const unsigned short* __restrict__ kh, const unsigned short* __restrict__ km,
    const unsigned short* __restrict__ mh, const unsigned short* __restrict__ mm_,
    const float* __restrict__ invn,
    float* __restrict__ pV1, int* __restrict__ pI1, float* __restrict__ pV2)
{
    __shared__ short T[4][128 * 32];   // 0..1 = key h/m, 2..3 = mem h/m
    __shared__ float sInv[128];
    __shared__ float bV1[128][2];
    __shared__ int   bI1[128][2];
    __shared__ float bV2[128][2];

    // bijective XCD swizzle (nwg = 3584 = 8*448)
    const int orig = blockIdx.x;
    const int wg   = (orig & 7) * 448 + (orig >> 3);
    const int by   = wg & 3;          // k-block (fastest: key-tile sharers adjacent)
    const int bx   = (wg >> 2) & 63;  // b-block
    const int s    = wg >> 8;

    const int t    = threadIdx.x;
    const int b0   = bx * 128;
    const int n0   = by * 128;
    const int w    = t >> 6;
    const int lane = t & 63;
    const int wm   = w >> 1, wn = w & 1;
    const int lr   = lane & 15, lg = lane >> 4;

    const size_t sB = (size_t)s * B_;
    const size_t sK = (size_t)s * K_;

    const unsigned short* __restrict__ APl[2] = { kh, km };
    const unsigned short* __restrict__ BPl[2] = { mh, mm_ };

    fx4 acc[4][4];
    #pragma unroll
    for (int i = 0; i < 4; ++i)
        #pragma unroll
        for (int j = 0; j < 4; ++j) acc[i][j] = (fx4)0.0f;

    // staging: lane covers (row = l>>2, phys chunk = l&3);
    // pre-swizzled source chunk = (l&3) ^ ((l>>3)&3)
    const int rsub = lane >> 2;
    const int csw  = (((lane & 3) ^ ((lane >> 3) & 3)) * 8);
    // read-side: phys chunk = lg ^ ((row>>1)&3)
    const int rdof = ((lg ^ ((lr >> 1) & 3)) * 8);

    for (int dc = 0; dc < 8; ++dc) {
        // ---- stage 4 tiles (8 gload16/thread) ----
        const int dco = dc * 32 + csw;
        #pragma unroll
        for (int p = 0; p < 2; ++p) {
            #pragma unroll
            for (int u = 0; u < 2; ++u) {
                const int R0 = w * 32 + u * 16;
                gload16(APl[p] + (sB + b0 + R0 + rsub) * D_ + dco, &T[p][R0 * 32]);
                gload16(BPl[p] + (sK + n0 + R0 + rsub) * D_ + dco, &T[2 + p][R0 * 32]);
            }
        }
        __syncthreads();   // vmcnt(0) drain: all 4 tiles resident

        // ---- hoist B fragments once (8 ds_read_b128) ----
        bfx8 bf[2][4];
        #pragma unroll
        for (int bp = 0; bp < 2; ++bp)
            #pragma unroll
            for (int j = 0; j < 4; ++j)
                bf[bp][j] = *reinterpret_cast<const bfx8*>(
                    &T[2 + bp][(wn * 64 + j * 16 + lr) * 32 + rdof]);

        // ---- 3 term-pairs: (0,0)(0,1)(1,0) ----
        #pragma unroll
        for (int ap = 0; ap < 2; ++ap) {
            bfx8 af[4];
            #pragma unroll
            for (int i = 0; i < 4; ++i)
                af[i] = *reinterpret_cast<const bfx8*>(
                    &T[ap][(wm * 64 + i * 16 + lr) * 32 + rdof]);
            #pragma unroll
            for (int bp = 0; bp < 2 - ap; ++bp) {
                __builtin_amdgcn_s_setprio(1);
                #pragma unroll
                for (int i = 0; i < 4; ++i)
                    #pragma unroll
                    for (int j = 0; j < 4; ++j)
                        acc[i][j] = __builtin_amdgcn_mfma_f32_16x16x32_bf16(
                            af[i], bf[bp][j], acc[i][j], 0, 0, 0);
                __builtin_amdgcn_s_setprio(0);
            }
        }
        __syncthreads();   // everyone done reading before next stage overwrites
    }

    if (t < 128) sInv[t] = invn[sK + n0 + t];
    __syncthreads();

    #pragma unroll
    for (int i = 0; i < 4; ++i) {
        #pragma unroll
        for (int r = 0; r < 4; ++r) {
            float v1 = -3.4e38f, v2 = -3.4e38f; int i1 = 0x7fffffff;
            #pragma unroll
            for (int j = 0; j < 4; ++j) {
                const int kloc = wn * 64 + j * 16 + lr;
                const float v  = acc[i][j][r] * sInv[kloc];
                const int  kg  = n0 + kloc;
                if (v > v1 || (v == v1 && kg < i1)) { v2 = v1; v1 = v; i1 = kg; }
                else if (v > v2) v2 = v;
            }
            #pragma unroll
            for (int msk = 1; msk < 16; msk <<= 1) {
                const float ov1 = __shfl_xor(v1, msk, 64);
                const int   oi1 = __shfl_xor(i1, msk, 64);
                const float ov2 = __shfl_xor(v2, msk, 64);
                const bool op = (ov1 > v1) || (ov1 == v1 && oi1 < i1);
                if (op) { v2 = fmaxf(v1, ov2); v1 = ov1; i1 = oi1; }
                else    { v2 = fmaxf(ov1, v2); }
            }
            if (lr == 0) {
                const int mrow = wm * 64 + i * 16 + lg * 4 + r;
                bV1[mrow][wn] = v1; bI1[mrow][wn] = i1; bV2[mrow][wn] = v2;
            }
        }
    }
    __syncthreads();

    if (t < 128) {
        float v1 = bV1[t][0]; int i1 = bI1[t][0]; float v2 = bV2[t][0];
        const float ov1 = bV1[t][1]; const int oi1 = bI1[t][1]; const float ov2 = bV2[t][1];
        const bool op = (ov1 > v1) || (ov1 == v1 && oi1 < i1);
        if (op) { v2 = fmaxf(v1, ov2); v1 = ov1; i1 = oi1; }
        else    { v2 = fmaxf(ov1, v2); }
        const size_t o = ((size_t)s * 4 + by) * B_ + b0 + t;
        pV1[o] = v1; pI1[o] = i1; pV2[o] = v2;
    }
}

// ---------------------------------------------------------------------------
// merge 4 n-block top-2 partials -> ind; flag ambiguous rows (gap < 2*eps)
// [round-9 verified -- VERBATIM]
// ---------------------------------------------------------------------------
__global__ __launch_bounds__(256) void combine_cert_kernel(
    const float* __restrict__ pV1, const int* __restrict__ pI1,
    const float* __restrict__ pV2, const float* __restrict__ keynorm,
    int* __restrict__ ind, int* __restrict__ ambCnt, int* __restrict__ ambList)
{
    const int idx = blockIdx.x * 256 + threadIdx.x;   // s*B + b
    const int s   = idx >> 13;                        // B_=8192
    const int b   = idx & 8191;
    float V1 = -3.4e38f, V2 = -3.4e38f; int I1 = 0x7fffffff;
    #pragma unroll
    for (int nb = 0; nb < 4; ++nb) {
        const size_t o = ((size_t)s * 4 + nb) * B_ + b;
        const float v1 = pV1[o]; const int i1 = pI1[o]; const float v2 = pV2[o];
        const bool op = (v1 > V1) || (v1 == V1 && i1 < I1);
        if (op) { V2 = fmaxf(V1, v2); V1 = v1; I1 = i1; }
        else    { V2 = fmaxf(v1, V2); }
    }
    ind[idx] = I1;
    const float eps = CERT_C * keynorm[idx];
    if (V1 - V2 < 2.0f * eps) {
        const int p = atomicAdd(ambCnt, 1);
        ambList[p] = idx;
    }
}

__global__ __launch_bounds__(64) void zero2_kernel(
    int* __restrict__ c1, int* __restrict__ c2)
{
    if (threadIdx.x == 0) { *c1 = 0; *c2 = 0; }
}

// ---------------------------------------------------------------------------
// exact fp64 rescore of ambiguous rows -- coalesced + BLOCK-SKIP.
// One row per block; wave w scans ks [128w,128w+128) = partial-block w.
// Skip wave if pV1[block w] < V1 - 2eps: every k there has
// true_k <= v1_w + eps < V1 - eps <= true_I1 (strict) -> provably not the
// argmax nor tied.  Surviving-block scan identical to round-9 verified code.
// ---------------------------------------------------------------------------
__global__ __launch_bounds__(256) void rescore_kernel(
    const int* __restrict__ ambCnt, const int* __restrict__ ambList,
    const float* __restrict__ key, const float* __restrict__ mem,
    const float* __restrict__ invn, const float* __restrict__ pV1,
    const float* __restrict__ keynorm, int* __restrict__ ind)
{
    __shared__ double sV[4];
    __shared__ int    sI[4];
    __shared__ float  sW[4];
    const int n    = *ambCnt;
    const int t    = threadIdx.x;
    const int w    = t >> 6;
    const int lane = t & 63;
    for (int li = blockIdx.x; li < n; li += gridDim.x) {
        const int row = ambList[li];
        const int s = row >> 13, b = row & 8191;

        // block-skip window
        const float v1w = pV1[((size_t)s * 4 + w) * B_ + b];
        if (lane == 0) sW[w] = v1w;
        __syncthreads();
        const float V1 = fmaxf(fmaxf(sW[0], sW[1]), fmaxf(sW[2], sW[3]));
        const float thr = V1 - 2.0f * CERT_C * keynorm[row];

        double bv = -1.0e300; int bk = 0x7fffffff;
        if (v1w >= thr) {
            const float4 kv = *reinterpret_cast<const float4*>(
                key + ((size_t)b * S_ + s) * D_ + lane * 4);
            const double k0 = kv.x, k1 = kv.y, k2 = kv.z, k3 = kv.w;
            const float* __restrict__ mbase = mem + (size_t)s * K_ * D_;
            const float* __restrict__ ibase = invn + (size_t)s * K_;
            for (int kq = 0; kq < 128; kq += 4) {
                double d[4];
                #pragma unroll
                for (int u = 0; u < 4; ++u) {
                    const int k = w * 128 + kq + u;
                    const float4 mv = *reinterpret_cast<const float4*>(
                        mbase + (size_t)k * D_ + lane * 4);
                    d[u] = k0 * mv.x + k1 * mv.y + k2 * mv.z + k3 * mv.w;
                }
                #pragma unroll
                for (int m = 32; m >= 1; m >>= 1)
                    #pragma unroll
                    for (int u = 0; u < 4; ++u) d[u] += __shfl_xor(d[u], m, 64);
                #pragma unroll
                for (int u = 0; u < 4; ++u) {
                    const int k = w * 128 + kq + u;
                    const double sc = d[u] * (double)ibase[k];
                    if (sc > bv || (sc == bv && k < bk)) { bv = sc; bk = k; }
                }
            }
        }
        if (lane == 0) { sV[w] = bv; sI[w] = bk; }
        __syncthreads();
        if (t == 0) {
            double v = sV[0]; int bi = sI[0];
            #pragma unroll
            for (int g = 1; g < 4; ++g)
                if (sV[g] > v || (sV[g] == v && sI[g] < bi)) { v = sV[g]; bi = sI[g]; }
            ind[row] = bi;
        }
        __syncthreads();
    }
}

// ---------------------------------------------------------------------------
// out[b][s][:] = value[b][0][:] + newmem[s][ind2[s*B+b]][:]
// ---------------------------------------------------------------------------
__global__ __launch_bounds__(256) void gather_out_kernel(
    const int* __restrict__ ind2, const float* __restrict__ value,
    const float* __restrict__ newmem, float* __restrict__ out)
{
    const int row  = blockIdx.x * 4 + (threadIdx.x >> 6);  // s*B + b
    const int lane = threadIdx.x & 63;
    const int s    = row >> 13;
    const int b    = row & 8191;
    const int bi   = ind2[row];
    const float4 vv = *reinterpret_cast<const float4*>(
        value + (size_t)b * (S_ * D_) + lane * 4);          // value[b][0][:]
    const float4 mmv = *reinterpret_cast<const float4*>(
        newmem + ((size_t)s * K_ + bi) * D_ + lane * 4);
    float4 o4;
    o4.x = vv.x + mmv.x; o4.y = vv.y + mmv.y;
    o4.z = vv.z + mmv.z; o4.w = vv.w + mmv.w;
    *reinterpret_cast<float4*>(out + ((size_t)b * S_ + s) * D_ + lane * 4) = o4;
}

// ---------------------------------------------------------------------------
// update chain: deterministic chunked counting sort + gather-EMA (unchanged)
// ---------------------------------------------------------------------------
__global__ __launch_bounds__(256) void u1_hist_kernel(
    const int* __restrict__ ind1, int* __restrict__ hist)
{
    __shared__ int h[K_];
    const int t = threadIdx.x, c = blockIdx.x, s = blockIdx.y;
    h[t] = 0; h[t + 256] = 0;
    __syncthreads();
    const int k = ind1[(size_t)s * B_ + c * 256 + t];
    atomicAdd(&h[k], 1);
    __syncthreads();
    hist[((size_t)s * 32 + c) * K_ + t]       = h[t];
    hist[((size_t)s * 32 + c) * K_ + t + 256] = h[t + 256];
}

__global__ __launch_bounds__(512) void u2_scan_kernel(
    int* __restrict__ hist, int* __restrict__ cnt, int* __restrict__ offs)
{
    __shared__ int sc[K_];
    const int k = threadIdx.x, s = blockIdx.x;
    int run = 0;
    for (int c = 0; c < 32; ++c) {
        const size_t o = ((size_t)s * 32 + c) * K_ + k;
        const int x = hist[o];
        hist[o] = run;           // exclusive per-chunk base within slot
        run += x;
    }
    cnt[s * K_ + k] = run;
    sc[k] = run;
    __syncthreads();
    for (int off = 1; off < K_; off <<= 1) {
        int v = (k >= off) ? sc[k - off] : 0;
        __syncthreads();
        sc[k] += v;
        __syncthreads();
    }
    offs[s * K_ + k] = sc[k] - run;   // exclusive slot base
}

__global__ __launch_bounds__(256) void u3_scatter_kernel(
    const int* __restrict__ ind1, const int* __restrict__ hist,
    const int* __restrict__ offs, int* __restrict__ csr)
{
    __shared__ int sk[256];
    const int t = threadIdx.x, c = blockIdx.x, s = blockIdx.y;
    const int b = c * 256 + t;
    const int k = ind1[(size_t)s * B_ + b];
    sk[t] = k;
    __syncthreads();
    int rank = 0;
    for (int j = 0; j < t; ++j) rank += (sk[j] == k);
    const int pos = offs[s * K_ + k] + hist[((size_t)s * 32 + c) * K_ + k] + rank;
    csr[(size_t)s * B_ + pos] = b;
}

__global__ __launch_bounds__(64) void u4_gather_kernel(
    const int* __restrict__ csr, const int* __restrict__ cnt,
    const int* __restrict__ offs, const float* __restrict__ value,
    const float* __restrict__ memory, float* __restrict__ newmem)
{
    const int k = blockIdx.x, s = blockIdx.y, lane = threadIdx.x;
    const int n = cnt[s * K_ + k];
    const int base = offs[s * K_ + k];
    float4 a; a.x = a.y = a.z = a.w = 0.0f;
    for (int i = 0; i < n; ++i) {
        const int b = csr[(size_t)s * B_ + base + i];
        const float4 v = *reinterpret_cast<const float4*>(
            value + ((size_t)b * S_ + s) * D_ + lane * 4);
        a.x += v.x; a.y += v.y; a.z += v.z; a.w += v.w;
    }
    const float inv = 1.0f / ((float)n + 1e-6f);
    const size_t o = ((size_t)s * K_ + k) * D_ + lane * 4;
    const float4 mo = *reinterpret_cast<const float4*>(memory + o);
    float4 r;
    r.x = mo.x * 0.999f + a.x * inv * 0.001f;
    r.y = mo.y * 0.999f + a.y * inv * 0.001f;
    r.z = mo.z * 0.999f + a.z * inv * 0.001f;
    r.w = mo.w * 0.999f + a.w * inv * 0.001f;
    *reinterpret_cast<float4*>(newmem + o) = r;
}

// ===========================================================================
// FALLBACK (round-1 verified fp32 path; used if ws too small)
// ===========================================================================
template <int MODE>
__global__ __launch_bounds__(256) void score_argmax_kernel(
    const float* __restrict__ key, const float* __restrict__ mem,
    const float* __restrict__ invn, const float* __restrict__ value,
    float* __restrict__ out, int* __restrict__ ind_out)
{
    __shared__ __align__(16) float kt[64][36];
    __shared__ __align__(16) float mt[64][36];
    __shared__ float redV[64][16];
    __shared__ int   redI[64][16];

    const int t  = threadIdx.x;
    const int s  = blockIdx.y;
    const int b0 = blockIdx.x * 64;
    const int tb = t & 15;
    const int tk = t >> 4;

    float best[4]; int bidx[4];
    #pragma unroll
    for (int i = 0; i < 4; ++i) { best[i] = -3.4e38f; bidx[i] = 0; }

    for (int kc = 0; kc < 8; ++kc) {
        float acc[4][4];
        #pragma unroll
        for (int i = 0; i < 4; ++i)
            #pragma unroll
            for (int j = 0; j < 4; ++j) acc[i][j] = 0.0f;

        for (int dc = 0; dc < 8; ++dc) {
            #pragma unroll
            for (int u = 0; u < 2; ++u) {
                const int f = t + u * 256;
                const int row = f >> 3;
                const int c4 = f & 7;
                *reinterpret_cast<float4*>(&kt[row][c4 * 4]) =
                    *reinterpret_cast<const float4*>(
                        key + (((size_t)(b0 + row)) * S_ + s) * D_ + dc * 32 + c4 * 4);
                *reinterpret_cast<float4*>(&mt[row][c4 * 4]) =
                    *reinterpret_cast<const float4*>(
                        mem + (((size_t)s * K_) + kc * 64 + row) * D_ + dc * 32 + c4 * 4);
            }
            __syncthreads();
            #pragma unroll
            for (int d4 = 0; d4 < 8; ++d4) {
                float4 a[4], b[4];
                #pragma unroll
                for (int i = 0; i < 4; ++i)
                    a[i] = *reinterpret_cast<const float4*>(&kt[tb + i * 16][d4 * 4]);
                #pragma unroll
                for (int j = 0; j < 4; ++j)
                    b[j] = *reinterpret_cast<const float4*>(&mt[tk + j * 16][d4 * 4]);
                #pragma unroll
                for (int i = 0; i < 4; ++i)
                    #pragma unroll
                    for (int j = 0; j < 4; ++j)
                        acc[i][j] += a[i].x * b[j].x + a[i].y * b[j].y +
                                     a[i].z * b[j].z + a[i].w * b[j].w;
            }
            __syncthreads();
        }
        #pragma unroll
        for (int j = 0; j < 4; ++j) {
            const int kabs = kc * 64 + tk + j * 16;
            const float inv = invn[s * K_ + kabs];
            #pragma unroll
            for (int i = 0; i < 4; ++i) {
                const float v = acc[i][j] * inv;
                if (v > best[i] || (v == best[i] && kabs < bidx[i])) {
                    best[i] = v; bidx[i] = kabs;
                }
            }
        }
    }
    #pragma unroll
    for (int i = 0; i < 4; ++i) {
        redV[tb + i * 16][tk] = best[i];
        redI[tb + i * 16][tk] = bidx[i];
    }
    __syncthreads();
    if (t < 64) {
        float bv = redV[t][0]; int bi = redI[t][0];
        #pragma unroll
        for (int g = 1; g < 16; ++g) {
            const float v = redV[t][g]; const int ix = redI[t][g];
            if (v > bv || (v == bv && ix < bi)) { bv = v; bi = ix; }
        }
        if (MODE == 0) ind_out[(size_t)s * B_ + b0 + t] = bi;
        else           redI[t][0] = bi;
    }
    if (MODE == 1) {
        __syncthreads();
        const int w = t >> 6, lane = t & 63;
        for (int r = w; r < 64; r += 4) {
            const int bg = b0 + r;
            const int kk = redI[r][0];
            const float4 vv = *reinterpret_cast<const float4*>(
                value + (size_t)bg * (S_ * D_) + lane * 4);
            const float4 mmv = *reinterpret_cast<const float4*>(
                mem + ((size_t)s * K_ + kk) * D_ + lane * 4);
            float4 o;
            o.x = vv.x + mmv.x; o.y = vv.y + mmv.y;
            o.z = vv.z + mmv.z; o.w = vv.w + mmv.w;
            *reinterpret_cast<float4*>(
                out + (((size_t)bg) * S_ + s) * D_ + lane * 4) = o;
        }
    }
}

__global__ __launch_bounds__(256) void update_kernel(
    const int* __restrict__ ind1, const float* __restrict__ value,
    const float* __restrict__ memory, float* __restrict__ newmem)
{
    const int k0 = blockIdx.x * 4, s = blockIdx.y, t = threadIdx.x;
    __shared__ int sIdx[256];
    float a0 = 0.f, a1 = 0.f, a2 = 0.f, a3 = 0.f;
    int c0 = 0, c1 = 0, c2 = 0, c3 = 0;
    for (int b0 = 0; b0 < B_; b0 += 256) {
        sIdx[t] = ind1[(size_t)s * B_ + b0 + t];
        __syncthreads();
        for (int bb = 0; bb < 256; ++bb) {
            const int ix = sIdx[bb];
            const unsigned r = (unsigned)(ix - k0);
            if (r < 4u) {
                const float v = value[(((size_t)(b0 + bb)) * S_ + s) * D_ + t];
                if      (r == 0u) { a0 += v; ++c0; }
                else if (r == 1u) { a1 += v; ++c1; }
                else if (r == 2u) { a2 += v; ++c2; }
                else              { a3 += v; ++c3; }
            }
        }
        __syncthreads();
    }
    const float accs[4] = { a0, a1, a2, a3 };
    const int   cns [4] = { c0, c1, c2, c3 };
    #pragma unroll
    for (int kk = 0; kk < 4; ++kk) {
        const size_t off = ((size_t)s * K_ + k0 + kk) * D_ + t;
        const float mean = accs[kk] / ((float)cns[kk] + 1e-6f);
        newmem[off] = memory[off] * 0.999f + mean * 0.001f;
    }
}

// ---------------------------------------------------------------------------
extern "C" void kernel_launch(void* const* d_in, const int* in_sizes, int n_in,
                              void* d_out, int out_size, void* d_ws, size_t ws_size,
                              hipStream_t stream)
{
    const float* key    = (const float*)d_in[0];
    const float* value  = (const float*)d_in[1];
    const float* memory = (const float*)d_in[2];

    float* out    = (float*)d_out;                       // (B,S,D)
    float* newmem = out + (size_t)B_ * S_ * D_;          // (S,K,D)

    // ---- workspace layout for the MFMA path ----
    const size_t keyPlane = (size_t)S_ * B_ * D_;        // elems (bf16)
    const size_t memPlane = (size_t)S_ * K_ * D_;
    char* p = (char*)d_ws;
    size_t need = 0;
    auto alloc = [&](size_t bytes) -> char* {
        char* r = p + need;
        need += (bytes + 255) & ~(size_t)255;
        return r;
    };
    unsigned short* kh   = (unsigned short*)alloc(keyPlane * 2);
    unsigned short* km   = (unsigned short*)alloc(keyPlane * 2);
    unsigned short* mh   = (unsigned short*)alloc(memPlane * 2);
    unsigned short* mm   = (unsigned short*)alloc(memPlane * 2);
    float* invn    = (float*)alloc((size_t)S_ * K_ * 4);
    float* keynorm = (float*)alloc((size_t)S_ * B_ * 4);
    float* pV1     = (float*)alloc((size_t)S_ * 4 * B_ * 4);
    int*   pI1     = (int*)  alloc((size_t)S_ * 4 * B_ * 4);
    float* pV2     = (float*)alloc((size_t)S_ * 4 * B_ * 4);
    int*   ind1    = (int*)  alloc((size_t)S_ * B_ * 4);
    int*   ind2    = (int*)  alloc((size_t)S_ * B_ * 4);
    int*   amb1Cnt = (int*)  alloc(256);
    int*   amb2Cnt = (int*)  alloc(256);
    int*   amb1Lst = (int*)  alloc((size_t)S_ * B_ * 4);
    int*   amb2Lst = (int*)  alloc((size_t)S_ * B_ * 4);
    int*   hist    = (int*)  alloc((size_t)S_ * 32 * K_ * 4);
    int*   cnt     = (int*)  alloc((size_t)S_ * K_ * 4);
    int*   offs    = (int*)  alloc((size_t)S_ * K_ * 4);
    int*   csr     = (int*)  alloc((size_t)S_ * B_ * 4);

    if (ws_size >= need) {
        // ================= fast MFMA path =================
        split_key2_kernel<<<dim3(B_ / 4, S_), 256, 0, stream>>>(key, kh, km, keynorm);
        splitnorm_mem2_kernel<<<dim3(S_ * K_), 64, 0, stream>>>(memory, mh, mm, invn);
        zero2_kernel<<<dim3(1), 64, 0, stream>>>(amb1Cnt, amb2Cnt);

        gemm_argmax3_kernel<<<dim3(3584), 256, 0, stream>>>(
            kh, km, mh, mm, invn, pV1, pI1, pV2);
        combine_cert_kernel<<<dim3((S_ * B_) / 256), 256, 0, stream>>>(
            pV1, pI1, pV2, keynorm, ind1, amb1Cnt, amb1Lst);
        rescore_kernel<<<dim3(1024), 256, 0, stream>>>(
            amb1Cnt, amb1Lst, key, memory, invn, pV1, keynorm, ind1);

        u1_hist_kernel<<<dim3(32, S_), 256, 0, stream>>>(ind1, hist);
        u2_scan_kernel<<<dim3(S_), 512, 0, stream>>>(hist, cnt, offs);
        u3_scatter_kernel<<<dim3(32, S_), 256, 0, stream>>>(ind1, hist, offs, csr);
        u4_gather_kernel<<<dim3(K_, S_), 64, 0, stream>>>(csr, cnt, offs, value, memory, newmem);

        splitnorm_mem2_kernel<<<dim3(S_ * K_), 64, 0, stream>>>(newmem, mh, mm, invn);

        gemm_argmax3_kernel<<<dim3(3584), 256, 0, stream>>>(
            kh, km, mh, mm, invn, pV1, pI1, pV2);
        combine_cert_kernel<<<dim3((S_ * B_) / 256), 256, 0, stream>>>(
            pV1, pI1, pV2, keynorm, ind2, amb2Cnt, amb2Lst);
        rescore_kernel<<<dim3(1024), 256, 0, stream>>>(
            amb2Cnt, amb2Lst, key, newmem, invn, pV1, keynorm, ind2);

        gather_out_kernel<<<dim3((S_ * B_) / 4), 256, 0, stream>>>(
            ind2, value, newmem, out);
    } else {
        // ================= fallback fp32 path (round-1, verified) =================
        float* invn1 = (float*)d_ws;
        float* invn2 = invn1 + S_ * K_;
        int*   find1 = (int*)(invn2 + S_ * K_);

        rownorm_kernel<<<dim3(S_ * K_), 64, 0, stream>>>(memory, invn1);
        score_argmax_kernel<0><<<dim3(B_ / 64, S_), 256, 0, stream>>>(
            key, memory, invn1, nullptr, nullptr, find1);
        update_kernel<<<dim3(K_ / 4, S_), 256, 0, stream>>>(find1, value, memory, newmem);
        rownorm_kernel<<<dim3(S_ * K_), 64, 0, stream>>>(newmem, invn2);
        score_argmax_kernel<1><<<dim3(B_ / 64, S_), 256, 0, stream>>>(
            key, newmem, invn2, value, out, nullptr);
    }
}